// Round 1
// baseline (371.755 us; speedup 1.0000x reference)
//
#include <hip/hip_runtime.h>
#include <stdint.h>

#define Bv 4
#define Nv 2048
#define Kv 30
#define DIMv 128
#define NROW (Bv * Nv)
#define NEDGE (Bv * Nv * Kv)

// ---------------- Kernel A: O frame precompute -> ws ----------------
__global__ __launch_bounds__(256) void o_kernel(const float* __restrict__ X,
                                                float* __restrict__ O9) {
    int id = blockIdx.x * 256 + threadIdx.x;
    if (id >= NROW) return;
    int b = id >> 11;
    int n = id & (Nv - 1);
    float o[9] = {0.f, 0.f, 0.f, 0.f, 0.f, 0.f, 0.f, 0.f, 0.f};
    if (n >= 1 && n <= Nv - 3) {
        const float* Xb = X + (size_t)b * Nv * 3;
        float lx = Xb[(Nv - 1) * 3 + 0], ly = Xb[(Nv - 1) * 3 + 1], lz = Xb[(Nv - 1) * 3 + 2];
        // u_2 = normalize(X[n] - X[N-1]);  u_1 = normalize(X[n+1] - X[N-1])
        float ax = Xb[n * 3 + 0] - lx, ay = Xb[n * 3 + 1] - ly, az = Xb[n * 3 + 2] - lz;
        float bx = Xb[(n + 1) * 3 + 0] - lx, by = Xb[(n + 1) * 3 + 1] - ly, bz = Xb[(n + 1) * 3 + 2] - lz;
        float an = fmaxf(sqrtf(ax * ax + ay * ay + az * az), 1e-12f);
        ax /= an; ay /= an; az /= an;
        float bn = fmaxf(sqrtf(bx * bx + by * by + bz * bz), 1e-12f);
        bx /= bn; by /= bn; bz /= bn;
        // n_2 = normalize(cross(u_2, u_1))
        float cx = ay * bz - az * by, cy = az * bx - ax * bz, cz = ax * by - ay * bx;
        float cn = fmaxf(sqrtf(cx * cx + cy * cy + cz * cz), 1e-12f);
        cx /= cn; cy /= cn; cz /= cn;
        // o_1 = normalize(u_2 - u_1)
        float ox = ax - bx, oy = ay - by, oz = az - bz;
        float on = fmaxf(sqrtf(ox * ox + oy * oy + oz * oz), 1e-12f);
        ox /= on; oy /= on; oz /= on;
        // third = cross(o_1, n_2)
        float tx = oy * cz - oz * cy, ty = oz * cx - ox * cz, tz = ox * cy - oy * cx;
        // columns are (o_1, n_2, third); row-major 3x3
        o[0] = ox; o[1] = cx; o[2] = tx;
        o[3] = oy; o[4] = cy; o[5] = ty;
        o[6] = oz; o[7] = cz; o[8] = tz;
    }
#pragma unroll
    for (int i = 0; i < 9; ++i) O9[(size_t)id * 9 + i] = o[i];
}

// ---------------- Kernel B: top-K per row (1 wave / row) ----------------
__global__ __launch_bounds__(256) void topk_kernel(const float* __restrict__ X,
                                                   const float* __restrict__ mask,
                                                   int* __restrict__ idx_ws,
                                                   float* __restrict__ dn_ws,
                                                   float* __restrict__ idxf_out) {
    const int lane = threadIdx.x & 63;
    const int wv = threadIdx.x >> 6;
    const int row = blockIdx.x * 4 + wv;   // row = b*N + n
    const int b = row >> 11;
    const int n = row & (Nv - 1);
    const float* Xb = X + (size_t)b * Nv * 3;
    const float* Mb = mask + (size_t)b * Nv;
    const float xn = Xb[n * 3 + 0], yn = Xb[n * 3 + 1], zn = Xb[n * 3 + 2];
    const float mi = Mb[n];

    uint32_t vb[32];
    float dmax = 0.f;
#pragma unroll
    for (int w = 0; w < 32; ++w) {
        int j = w * 64 + lane;
        // exact order, no fma contraction, to bit-match numpy reference
        float dx = __fsub_rn(xn, Xb[j * 3 + 0]);
        float dy = __fsub_rn(yn, Xb[j * 3 + 1]);
        float dz = __fsub_rn(zn, Xb[j * 3 + 2]);
        float s = __fadd_rn(__fadd_rn(__fmul_rn(dx, dx), __fmul_rn(dy, dy)), __fmul_rn(dz, dz));
        float D = __fmul_rn(__fmul_rn(mi, Mb[j]), __fsqrt_rn(__fadd_rn(s, 1e-6f)));
        vb[w] = __float_as_uint(D);
        dmax = fmaxf(dmax, D);
    }
    // wave-wide row max (exact: max is order independent)
#pragma unroll
    for (int m = 1; m < 64; m <<= 1) dmax = fmaxf(dmax, __shfl_xor(dmax, m, 64));
    // D_adjust = D + (1 - mask2) * D_max   (exact +0.0 when mask==1)
#pragma unroll
    for (int w = 0; w < 32; ++w) {
        int j = w * 64 + lane;
        float D = __uint_as_float(vb[w]);
        float m2 = __fmul_rn(mi, Mb[j]);
        float adj = __fadd_rn(D, __fmul_rn(__fsub_rn(1.f, m2), dmax));
        vb[w] = __float_as_uint(adj);
    }

    // per-lane min (strict < keeps lowest w on ties)
    uint32_t bestv = 0xFFFFFFFFu;
    int bestw = 0;
#pragma unroll
    for (int w = 0; w < 32; ++w)
        if (vb[w] < bestv) { bestv = vb[w]; bestw = w; }
    unsigned long long key =
        ((unsigned long long)bestv << 32) | (unsigned)(bestw * 64 + lane);

    const int rk = row * Kv;
    for (int p = 0; p < Kv; ++p) {
        unsigned long long kmin = key;
#pragma unroll
        for (int m = 1; m < 64; m <<= 1) {
            unsigned long long o = __shfl_xor(kmin, m, 64);
            kmin = (o < kmin) ? o : kmin;
        }
        unsigned jsel = (unsigned)(kmin & 0xFFFFFFFFull);
        if (lane == 0) {
            idx_ws[rk + p] = (int)jsel;
            dn_ws[rk + p] = __uint_as_float((uint32_t)(kmin >> 32));
            idxf_out[rk + p] = (float)jsel;
        }
        // invalidate chosen slot (only owner lane matches), rescan
#pragma unroll
        for (int w = 0; w < 32; ++w)
            if ((unsigned)(w * 64 + lane) == jsel) vb[w] = 0xFFFFFFFFu;
        bestv = 0xFFFFFFFFu;
        bestw = 0;
#pragma unroll
        for (int w = 0; w < 32; ++w)
            if (vb[w] < bestv) { bestv = vb[w]; bestw = w; }
        key = ((unsigned long long)bestv << 32) | (unsigned)(bestw * 64 + lane);
    }
}

// ---------------- Kernel C: features + (39x128) dot + LayerNorm ----------------
__device__ __forceinline__ float sgnf(float x) {
    return (x > 0.f) ? 1.f : ((x < 0.f) ? -1.f : 0.f);
}

__global__ __launch_bounds__(256) void edge_kernel(const float* __restrict__ X,
                                                   const float* __restrict__ W,
                                                   const float* __restrict__ be,
                                                   const float* __restrict__ gain,
                                                   const float* __restrict__ bias,
                                                   const float* __restrict__ O9,
                                                   const int* __restrict__ idx_ws,
                                                   const float* __restrict__ dn_ws,
                                                   float* __restrict__ E) {
    __shared__ float sf[2][40];
    __shared__ float sr1[2][2];
    __shared__ float sr2[2][2];
    const int eg = threadIdx.x >> 7;        // which edge in block
    const int t = threadIdx.x & 127;        // channel
    const int e = blockIdx.x * 2 + eg;
    const int b = e / (Nv * Kv);
    const int r2 = e - b * (Nv * Kv);
    const int n = r2 / Kv;
    const int idx = idx_ws[e];
    const float dn = dn_ws[e];

    if (t < 8) {
        const float c = -0.5756462732485115f;  // -ln(10000)/16
        float freq = expf((float)(2 * t) * c);
        float ang = ((float)idx - (float)n) * freq;
        sf[eg][t] = cosf(ang);
        sf[eg][t + 8] = sinf(ang);
    } else if (t >= 16 && t < 32) {
        int r = t - 16;
        float mu = (float)r * (20.0f / 15.0f);  // linspace(0,20,16)
        float z = (dn - mu) * 0.8f;             // / 1.25
        sf[eg][16 + r] = expf(-z * z);
    } else if (t == 32) {
        float oi[9], oj[9];
#pragma unroll
        for (int i = 0; i < 9; ++i) {
            oi[i] = O9[((size_t)b * Nv + n) * 9 + i];
            oj[i] = O9[((size_t)b * Nv + idx) * 9 + i];
        }
        float dx = X[((size_t)b * Nv + idx) * 3 + 0] - X[((size_t)b * Nv + n) * 3 + 0];
        float dy = X[((size_t)b * Nv + idx) * 3 + 1] - X[((size_t)b * Nv + n) * 3 + 1];
        float dz = X[((size_t)b * Nv + idx) * 3 + 2] - X[((size_t)b * Nv + n) * 3 + 2];
        // dU = normalize(O . dXn)   (rows of O dot dXn)
        float u0 = oi[0] * dx + oi[1] * dy + oi[2] * dz;
        float u1 = oi[3] * dx + oi[4] * dy + oi[5] * dz;
        float u2 = oi[6] * dx + oi[7] * dy + oi[8] * dz;
        float un = fmaxf(sqrtf(u0 * u0 + u1 * u1 + u2 * u2), 1e-12f);
        sf[eg][32] = u0 / un;
        sf[eg][33] = u1 / un;
        sf[eg][34] = u2 / un;
        // R[i][l] = sum_j O[j][i] * Onb[j][l]
        float R00 = oi[0] * oj[0] + oi[3] * oj[3] + oi[6] * oj[6];
        float R11 = oi[1] * oj[1] + oi[4] * oj[4] + oi[7] * oj[7];
        float R22 = oi[2] * oj[2] + oi[5] * oj[5] + oi[8] * oj[8];
        float R21 = oi[2] * oj[1] + oi[5] * oj[4] + oi[8] * oj[7];
        float R12 = oi[1] * oj[2] + oi[4] * oj[5] + oi[7] * oj[8];
        float R02 = oi[0] * oj[2] + oi[3] * oj[5] + oi[6] * oj[8];
        float R20 = oi[2] * oj[0] + oi[5] * oj[3] + oi[8] * oj[6];
        float R10 = oi[1] * oj[0] + oi[4] * oj[3] + oi[7] * oj[6];
        float R01 = oi[0] * oj[1] + oi[3] * oj[4] + oi[6] * oj[7];
        float m0 = 0.5f * sqrtf(fabsf(1.0f + (R00 - R11 - R22)));
        float m1 = 0.5f * sqrtf(fabsf(1.0f + (-R00 + R11 - R22)));
        float m2 = 0.5f * sqrtf(fabsf(1.0f + (-R00 - R11 + R22)));
        float s0 = sgnf(R21 - R12);
        float s1 = sgnf(R02 - R20);
        float s2 = sgnf(R10 - R01);
        float tr = 1.0f + R00 + R11 + R22;
        float w4 = sqrtf(fmaxf(tr, 0.f)) * 0.5f;
        float q0 = s0 * m0, q1 = s1 * m1, q2 = s2 * m2;
        float qn = fmaxf(sqrtf(q0 * q0 + q1 * q1 + q2 * q2 + w4 * w4), 1e-12f);
        sf[eg][35] = q0 / qn;
        sf[eg][36] = q1 / qn;
        sf[eg][37] = q2 / qn;
        sf[eg][38] = w4 / qn;
    }
    __syncthreads();

    float acc = be[t];
#pragma unroll
    for (int i = 0; i < 39; ++i) acc = fmaf(sf[eg][i], W[i * DIMv + t], acc);

    // LayerNorm over 128 channels (2 waves)
    float v = acc;
#pragma unroll
    for (int m = 1; m < 64; m <<= 1) v += __shfl_xor(v, m, 64);
    const int ln = t & 63, wvq = t >> 6;
    if (ln == 0) sr1[eg][wvq] = v;
    __syncthreads();
    float mu = (sr1[eg][0] + sr1[eg][1]) * (1.0f / 128.0f);
    float d = acc - mu;
    float vv = d * d;
#pragma unroll
    for (int m = 1; m < 64; m <<= 1) vv += __shfl_xor(vv, m, 64);
    if (ln == 0) sr2[eg][wvq] = vv;
    __syncthreads();
    float sigma = sqrtf((sr2[eg][0] + sr2[eg][1]) * (1.0f / 127.0f));
    E[(size_t)e * DIMv + t] = gain[t] * d / (sigma + 1e-6f) + bias[t];
}

// ---------------- launcher ----------------
extern "C" void kernel_launch(void* const* d_in, const int* in_sizes, int n_in,
                              void* d_out, int out_size, void* d_ws, size_t ws_size,
                              hipStream_t stream) {
    const float* X = (const float*)d_in[0];
    const float* mask = (const float*)d_in[1];
    const float* W_e = (const float*)d_in[2];
    const float* b_e = (const float*)d_in[3];
    const float* gain = (const float*)d_in[4];
    const float* bias = (const float*)d_in[5];

    float* E = (float*)d_out;                                   // B*N*K*128
    float* idxf = (float*)d_out + (size_t)NEDGE * DIMv;         // B*N*K (as f32)

    char* ws = (char*)d_ws;
    float* O9 = (float*)ws;                                     // B*N*9
    int* idx_ws = (int*)(ws + (size_t)NROW * 9 * sizeof(float));
    float* dn_ws = (float*)(ws + (size_t)NROW * 9 * sizeof(float) +
                            (size_t)NEDGE * sizeof(int));

    hipLaunchKernelGGL(o_kernel, dim3((NROW + 255) / 256), dim3(256), 0, stream, X, O9);
    hipLaunchKernelGGL(topk_kernel, dim3(NROW / 4), dim3(256), 0, stream,
                       X, mask, idx_ws, dn_ws, idxf);
    hipLaunchKernelGGL(edge_kernel, dim3(NEDGE / 2), dim3(256), 0, stream,
                       X, W_e, b_e, gain, bias, O9, idx_ws, dn_ws, E);
}

// Round 2
// 162.657 us; speedup vs baseline: 2.2855x; 2.2855x over previous
//
#include <hip/hip_runtime.h>
#include <stdint.h>

#define Bv 4
#define Nv 2048
#define Kv 30
#define DIMv 128
#define NROW (Bv * Nv)
#define NEDGE (Bv * Nv * Kv)

// ---------------- Kernel A: O frame precompute -> ws ----------------
__global__ __launch_bounds__(256) void o_kernel(const float* __restrict__ X,
                                                float* __restrict__ O9) {
    int id = blockIdx.x * 256 + threadIdx.x;
    if (id >= NROW) return;
    int b = id >> 11;
    int n = id & (Nv - 1);
    float o[9] = {0.f, 0.f, 0.f, 0.f, 0.f, 0.f, 0.f, 0.f, 0.f};
    if (n >= 1 && n <= Nv - 3) {
        const float* Xb = X + (size_t)b * Nv * 3;
        float lx = Xb[(Nv - 1) * 3 + 0], ly = Xb[(Nv - 1) * 3 + 1], lz = Xb[(Nv - 1) * 3 + 2];
        float ax = Xb[n * 3 + 0] - lx, ay = Xb[n * 3 + 1] - ly, az = Xb[n * 3 + 2] - lz;
        float bx = Xb[(n + 1) * 3 + 0] - lx, by = Xb[(n + 1) * 3 + 1] - ly, bz = Xb[(n + 1) * 3 + 2] - lz;
        float an = fmaxf(sqrtf(ax * ax + ay * ay + az * az), 1e-12f);
        ax /= an; ay /= an; az /= an;
        float bn = fmaxf(sqrtf(bx * bx + by * by + bz * bz), 1e-12f);
        bx /= bn; by /= bn; bz /= bn;
        float cx = ay * bz - az * by, cy = az * bx - ax * bz, cz = ax * by - ay * bx;
        float cn = fmaxf(sqrtf(cx * cx + cy * cy + cz * cz), 1e-12f);
        cx /= cn; cy /= cn; cz /= cn;
        float ox = ax - bx, oy = ay - by, oz = az - bz;
        float on = fmaxf(sqrtf(ox * ox + oy * oy + oz * oz), 1e-12f);
        ox /= on; oy /= on; oz /= on;
        float tx = oy * cz - oz * cy, ty = oz * cx - ox * cz, tz = ox * cy - oy * cx;
        o[0] = ox; o[1] = cx; o[2] = tx;
        o[3] = oy; o[4] = cy; o[5] = ty;
        o[6] = oz; o[7] = cz; o[8] = tz;
    }
#pragma unroll
    for (int i = 0; i < 9; ++i) O9[(size_t)id * 9 + i] = o[i];
}

// ---------------- Kernel B: top-K per row (1 wave / row), bit-exact ----------------
__global__ __launch_bounds__(256) void topk_kernel(const float* __restrict__ X,
                                                   const float* __restrict__ mask,
                                                   int* __restrict__ idx_ws,
                                                   float* __restrict__ dn_ws,
                                                   float* __restrict__ idxf_out) {
    const int lane = threadIdx.x & 63;
    const int wv = threadIdx.x >> 6;
    const int row = blockIdx.x * 4 + wv;
    const int b = row >> 11;
    const int n = row & (Nv - 1);
    const float* Xb = X + (size_t)b * Nv * 3;
    const float* Mb = mask + (size_t)b * Nv;
    const float xn = Xb[n * 3 + 0], yn = Xb[n * 3 + 1], zn = Xb[n * 3 + 2];
    const float mi = Mb[n];

    uint32_t vb[32];
    float dmax = 0.f;
#pragma unroll
    for (int w = 0; w < 32; ++w) {
        int j = w * 64 + lane;
        float dx = __fsub_rn(xn, Xb[j * 3 + 0]);
        float dy = __fsub_rn(yn, Xb[j * 3 + 1]);
        float dz = __fsub_rn(zn, Xb[j * 3 + 2]);
        float s = __fadd_rn(__fadd_rn(__fmul_rn(dx, dx), __fmul_rn(dy, dy)), __fmul_rn(dz, dz));
        float D = __fmul_rn(__fmul_rn(mi, Mb[j]), __fsqrt_rn(__fadd_rn(s, 1e-6f)));
        vb[w] = __float_as_uint(D);
        dmax = fmaxf(dmax, D);
    }
#pragma unroll
    for (int m = 1; m < 64; m <<= 1) dmax = fmaxf(dmax, __shfl_xor(dmax, m, 64));
#pragma unroll
    for (int w = 0; w < 32; ++w) {
        int j = w * 64 + lane;
        float D = __uint_as_float(vb[w]);
        float m2 = __fmul_rn(mi, Mb[j]);
        float adj = __fadd_rn(D, __fmul_rn(__fsub_rn(1.f, m2), dmax));
        vb[w] = __float_as_uint(adj);
    }

    uint32_t bestv = 0xFFFFFFFFu;
    int bestw = 0;
#pragma unroll
    for (int w = 0; w < 32; ++w)
        if (vb[w] < bestv) { bestv = vb[w]; bestw = w; }
    unsigned long long key =
        ((unsigned long long)bestv << 32) | (unsigned)(bestw * 64 + lane);

    const int rk = row * Kv;
    for (int p = 0; p < Kv; ++p) {
        unsigned long long kmin = key;
#pragma unroll
        for (int m = 1; m < 64; m <<= 1) {
            unsigned long long o = __shfl_xor(kmin, m, 64);
            kmin = (o < kmin) ? o : kmin;
        }
        unsigned jsel = (unsigned)(kmin & 0xFFFFFFFFull);
        if (lane == 0) {
            idx_ws[rk + p] = (int)jsel;
            dn_ws[rk + p] = __uint_as_float((uint32_t)(kmin >> 32));
            idxf_out[rk + p] = (float)jsel;
        }
#pragma unroll
        for (int w = 0; w < 32; ++w)
            if ((unsigned)(w * 64 + lane) == jsel) vb[w] = 0xFFFFFFFFu;
        bestv = 0xFFFFFFFFu;
        bestw = 0;
#pragma unroll
        for (int w = 0; w < 32; ++w)
            if (vb[w] < bestv) { bestv = vb[w]; bestw = w; }
        key = ((unsigned long long)bestv << 32) | (unsigned)(bestw * 64 + lane);
    }
}

// ---------------- Kernel C: block per (b,n): features + GEMM + LN ----------------
__device__ __forceinline__ float sgnf(float x) {
    return (x > 0.f) ? 1.f : ((x < 0.f) ? -1.f : 0.f);
}

__global__ __launch_bounds__(256) void edge_kernel(const float* __restrict__ X,
                                                   const float* __restrict__ W,
                                                   const float* __restrict__ be,
                                                   const float* __restrict__ gain,
                                                   const float* __restrict__ bias,
                                                   const float* __restrict__ O9,
                                                   const int* __restrict__ idx_ws,
                                                   const float* __restrict__ dn_ws,
                                                   float* __restrict__ E) {
    __shared__ float fls[Kv][40];      // 39 features per edge (+pad)
    __shared__ float els[Kv][DIMv];    // pre-LN outputs
    __shared__ float sO[9];
    __shared__ float sX[3];
    __shared__ int   sidx[Kv];
    __shared__ float sdn[Kv];

    const int t = threadIdx.x;
    const int row = blockIdx.x;            // b*N + n
    const int b = row >> 11;
    const int n = row & (Nv - 1);
    const int bN = b * Nv;
    const size_t ebase = (size_t)row * Kv;

    // ---- phase A: stage per-row data ----
    if (t < Kv) {
        sidx[t] = idx_ws[ebase + t];
        sdn[t] = dn_ws[ebase + t];
    } else if (t >= 32 && t < 41) {
        sO[t - 32] = O9[(size_t)row * 9 + (t - 32)];
    } else if (t >= 48 && t < 51) {
        sX[t - 48] = X[(size_t)row * 3 + (t - 48)];
    }
    __syncthreads();

    // ---- phase B: features ----
    if (t < 240) {
        const int e = t >> 3;
        const int p = t & 7;
        // positional encodings: cos/sin of (idx-n)*freq_p
        const float c = -0.5756462732485115f;  // -ln(10000)/16
        float freq = expf((float)(2 * p) * c);
        float ang = ((float)sidx[e] - (float)n) * freq;
        fls[e][p] = cosf(ang);
        fls[e][p + 8] = sinf(ang);
        // RBF: r = p and p+8
        float dn = sdn[e];
        float mu0 = (float)p * (20.0f / 15.0f);
        float z0 = (dn - mu0) * 0.8f;
        fls[e][16 + p] = expf(-z0 * z0);
        float mu1 = (float)(p + 8) * (20.0f / 15.0f);
        float z1 = (dn - mu1) * 0.8f;
        fls[e][24 + p] = expf(-z1 * z1);
    }
    if (t < Kv) {
        const int e = t;
        const int j = sidx[e];
        float oi[9], oj[9];
#pragma unroll
        for (int i = 0; i < 9; ++i) {
            oi[i] = sO[i];
            oj[i] = O9[((size_t)bN + j) * 9 + i];
        }
        float dx = X[((size_t)bN + j) * 3 + 0] - sX[0];
        float dy = X[((size_t)bN + j) * 3 + 1] - sX[1];
        float dz = X[((size_t)bN + j) * 3 + 2] - sX[2];
        float u0 = oi[0] * dx + oi[1] * dy + oi[2] * dz;
        float u1 = oi[3] * dx + oi[4] * dy + oi[5] * dz;
        float u2 = oi[6] * dx + oi[7] * dy + oi[8] * dz;
        float un = fmaxf(sqrtf(u0 * u0 + u1 * u1 + u2 * u2), 1e-12f);
        fls[e][32] = u0 / un;
        fls[e][33] = u1 / un;
        fls[e][34] = u2 / un;
        float R00 = oi[0] * oj[0] + oi[3] * oj[3] + oi[6] * oj[6];
        float R11 = oi[1] * oj[1] + oi[4] * oj[4] + oi[7] * oj[7];
        float R22 = oi[2] * oj[2] + oi[5] * oj[5] + oi[8] * oj[8];
        float R21 = oi[2] * oj[1] + oi[5] * oj[4] + oi[8] * oj[7];
        float R12 = oi[1] * oj[2] + oi[4] * oj[5] + oi[7] * oj[8];
        float R02 = oi[0] * oj[2] + oi[3] * oj[5] + oi[6] * oj[8];
        float R20 = oi[2] * oj[0] + oi[5] * oj[3] + oi[8] * oj[6];
        float R10 = oi[1] * oj[0] + oi[4] * oj[3] + oi[7] * oj[6];
        float R01 = oi[0] * oj[1] + oi[3] * oj[4] + oi[6] * oj[7];
        float m0 = 0.5f * sqrtf(fabsf(1.0f + (R00 - R11 - R22)));
        float m1 = 0.5f * sqrtf(fabsf(1.0f + (-R00 + R11 - R22)));
        float m2 = 0.5f * sqrtf(fabsf(1.0f + (-R00 - R11 + R22)));
        float s0 = sgnf(R21 - R12);
        float s1 = sgnf(R02 - R20);
        float s2 = sgnf(R10 - R01);
        float tr = 1.0f + R00 + R11 + R22;
        float w4 = sqrtf(fmaxf(tr, 0.f)) * 0.5f;
        float q0 = s0 * m0, q1 = s1 * m1, q2 = s2 * m2;
        float qn = fmaxf(sqrtf(q0 * q0 + q1 * q1 + q2 * q2 + w4 * w4), 1e-12f);
        fls[e][35] = q0 / qn;
        fls[e][36] = q1 / qn;
        fls[e][37] = q2 / qn;
        fls[e][38] = w4 / qn;
    }
    __syncthreads();

    // ---- phase C: GEMM 30x39 @ 39x128 ----
    {
        const int c = t & 127;
        const int h = t >> 7;   // edge half: 0 -> edges 0..14, 1 -> 15..29
        float w[39];
#pragma unroll
        for (int i = 0; i < 39; ++i) w[i] = W[i * DIMv + c];
        const float bec = be[c];
        const int e0 = h * 15;
#pragma unroll 3
        for (int e = e0; e < e0 + 15; ++e) {
            const float* fr = &fls[e][0];
            float acc = bec;
#pragma unroll
            for (int q = 0; q < 9; ++q) {
                float4 v = *(const float4*)(fr + 4 * q);
                acc = fmaf(v.x, w[4 * q + 0], acc);
                acc = fmaf(v.y, w[4 * q + 1], acc);
                acc = fmaf(v.z, w[4 * q + 2], acc);
                acc = fmaf(v.w, w[4 * q + 3], acc);
            }
            acc = fmaf(fr[36], w[36], acc);
            acc = fmaf(fr[37], w[37], acc);
            acc = fmaf(fr[38], w[38], acc);
            els[e][c] = acc;
        }
    }
    __syncthreads();

    // ---- phase D: LayerNorm (8 lanes per edge) + store ----
    if (t < 240) {
        const int e = t >> 3;
        const int l = t & 7;
        const float* er = &els[e][l * 16];
        float vals[16];
        float s = 0.f;
#pragma unroll
        for (int q = 0; q < 4; ++q) {
            float4 v = *(const float4*)(er + 4 * q);
            vals[4 * q + 0] = v.x; vals[4 * q + 1] = v.y;
            vals[4 * q + 2] = v.z; vals[4 * q + 3] = v.w;
            s += v.x + v.y + v.z + v.w;
        }
        s += __shfl_xor(s, 1, 64);
        s += __shfl_xor(s, 2, 64);
        s += __shfl_xor(s, 4, 64);
        float mu = s * (1.0f / 128.0f);
        float vv = 0.f;
#pragma unroll
        for (int j = 0; j < 16; ++j) {
            float d = vals[j] - mu;
            vals[j] = d;
            vv += d * d;
        }
        vv += __shfl_xor(vv, 1, 64);
        vv += __shfl_xor(vv, 2, 64);
        vv += __shfl_xor(vv, 4, 64);
        float sigma = sqrtf(vv * (1.0f / 127.0f));
        float inv = 1.0f / (sigma + 1e-6f);
        float* out = E + (ebase + e) * DIMv + l * 16;
        const float* gp = gain + l * 16;
        const float* bp = bias + l * 16;
#pragma unroll
        for (int q = 0; q < 4; ++q) {
            float4 g = *(const float4*)(gp + 4 * q);
            float4 bb = *(const float4*)(bp + 4 * q);
            float4 r;
            r.x = g.x * vals[4 * q + 0] * inv + bb.x;
            r.y = g.y * vals[4 * q + 1] * inv + bb.y;
            r.z = g.z * vals[4 * q + 2] * inv + bb.z;
            r.w = g.w * vals[4 * q + 3] * inv + bb.w;
            *(float4*)(out + 4 * q) = r;
        }
    }
}

// ---------------- launcher ----------------
extern "C" void kernel_launch(void* const* d_in, const int* in_sizes, int n_in,
                              void* d_out, int out_size, void* d_ws, size_t ws_size,
                              hipStream_t stream) {
    const float* X = (const float*)d_in[0];
    const float* mask = (const float*)d_in[1];
    const float* W_e = (const float*)d_in[2];
    const float* b_e = (const float*)d_in[3];
    const float* gain = (const float*)d_in[4];
    const float* bias = (const float*)d_in[5];

    float* E = (float*)d_out;
    float* idxf = (float*)d_out + (size_t)NEDGE * DIMv;

    char* ws = (char*)d_ws;
    float* O9 = (float*)ws;
    int* idx_ws = (int*)(ws + (size_t)NROW * 9 * sizeof(float));
    float* dn_ws = (float*)(ws + (size_t)NROW * 9 * sizeof(float) +
                            (size_t)NEDGE * sizeof(int));

    hipLaunchKernelGGL(o_kernel, dim3((NROW + 255) / 256), dim3(256), 0, stream, X, O9);
    hipLaunchKernelGGL(topk_kernel, dim3(NROW / 4), dim3(256), 0, stream,
                       X, mask, idx_ws, dn_ws, idxf);
    hipLaunchKernelGGL(edge_kernel, dim3(NROW), dim3(256), 0, stream,
                       X, W_e, b_e, gain, bias, O9, idx_ws, dn_ws, E);
}

// Round 3
// 125.080 us; speedup vs baseline: 2.9721x; 1.3004x over previous
//
#include <hip/hip_runtime.h>
#include <stdint.h>

#define Bv 4
#define Nv 2048
#define Kv 30
#define DIMv 128
#define NROW (Bv * Nv)
#define NEDGE (Bv * Nv * Kv)

// ---------------- Kernel A: O frame precompute -> ws ----------------
__global__ __launch_bounds__(256) void o_kernel(const float* __restrict__ X,
                                                float* __restrict__ O9) {
    int id = blockIdx.x * 256 + threadIdx.x;
    if (id >= NROW) return;
    int b = id >> 11;
    int n = id & (Nv - 1);
    float o[9] = {0.f, 0.f, 0.f, 0.f, 0.f, 0.f, 0.f, 0.f, 0.f};
    if (n >= 1 && n <= Nv - 3) {
        const float* Xb = X + (size_t)b * Nv * 3;
        float lx = Xb[(Nv - 1) * 3 + 0], ly = Xb[(Nv - 1) * 3 + 1], lz = Xb[(Nv - 1) * 3 + 2];
        float ax = Xb[n * 3 + 0] - lx, ay = Xb[n * 3 + 1] - ly, az = Xb[n * 3 + 2] - lz;
        float bx = Xb[(n + 1) * 3 + 0] - lx, by = Xb[(n + 1) * 3 + 1] - ly, bz = Xb[(n + 1) * 3 + 2] - lz;
        float an = fmaxf(sqrtf(ax * ax + ay * ay + az * az), 1e-12f);
        ax /= an; ay /= an; az /= an;
        float bn = fmaxf(sqrtf(bx * bx + by * by + bz * bz), 1e-12f);
        bx /= bn; by /= bn; bz /= bn;
        float cx = ay * bz - az * by, cy = az * bx - ax * bz, cz = ax * by - ay * bx;
        float cn = fmaxf(sqrtf(cx * cx + cy * cy + cz * cz), 1e-12f);
        cx /= cn; cy /= cn; cz /= cn;
        float ox = ax - bx, oy = ay - by, oz = az - bz;
        float on = fmaxf(sqrtf(ox * ox + oy * oy + oz * oz), 1e-12f);
        ox /= on; oy /= on; oz /= on;
        float tx = oy * cz - oz * cy, ty = oz * cx - ox * cz, tz = ox * cy - oy * cx;
        o[0] = ox; o[1] = cx; o[2] = tx;
        o[3] = oy; o[4] = cy; o[5] = ty;
        o[6] = oz; o[7] = cz; o[8] = tz;
    }
#pragma unroll
    for (int i = 0; i < 9; ++i) O9[(size_t)id * 9 + i] = o[i];
}

// ---------------- Kernel B: top-K per row (1 wave / row), bit-exact ----------------
// Values kept as 4 static groups of 8 per lane; cached per-group (min, slot).
// Per round: u32 value butterfly + u32 index-resolve butterfly; only the owner
// lane rescans its 8-slot group (4-arm branch, one lane active => execz skips).
__global__ __launch_bounds__(256) void topk_kernel(const float* __restrict__ X,
                                                   const float* __restrict__ mask,
                                                   int* __restrict__ idx_ws,
                                                   float* __restrict__ dn_ws,
                                                   float* __restrict__ idxf_out) {
    const int lane = threadIdx.x & 63;
    const int wv = threadIdx.x >> 6;
    const int row = blockIdx.x * 4 + wv;
    const int b = row >> 11;
    const int n = row & (Nv - 1);
    const float* Xb = X + (size_t)b * Nv * 3;
    const float* Mb = mask + (size_t)b * Nv;
    const float xn = Xb[n * 3 + 0], yn = Xb[n * 3 + 1], zn = Xb[n * 3 + 2];
    const float mi = Mb[n];

    // pass 1: exact D, row max
    float Dv[4][8];
    float dmax = 0.f;
#pragma unroll
    for (int gg = 0; gg < 4; ++gg)
#pragma unroll
        for (int s = 0; s < 8; ++s) {
            int j = (gg * 8 + s) * 64 + lane;
            float dx = __fsub_rn(xn, Xb[j * 3 + 0]);
            float dy = __fsub_rn(yn, Xb[j * 3 + 1]);
            float dz = __fsub_rn(zn, Xb[j * 3 + 2]);
            float ss = __fadd_rn(__fadd_rn(__fmul_rn(dx, dx), __fmul_rn(dy, dy)),
                                 __fmul_rn(dz, dz));
            float D = __fmul_rn(__fmul_rn(mi, Mb[j]), __fsqrt_rn(__fadd_rn(ss, 1e-6f)));
            Dv[gg][s] = D;
            dmax = fmaxf(dmax, D);
        }
#pragma unroll
    for (int m = 1; m < 64; m <<= 1) dmax = fmaxf(dmax, __shfl_xor(dmax, m, 64));

    // pass 2: D_adjust bits + per-group (min,slot) cache
    uint32_t g[4][8];
    uint32_t gmv[4], gmw[4];
#pragma unroll
    for (int gg = 0; gg < 4; ++gg) {
#pragma unroll
        for (int s = 0; s < 8; ++s) {
            int j = (gg * 8 + s) * 64 + lane;
            float m2 = __fmul_rn(mi, Mb[j]);
            float adj = __fadd_rn(Dv[gg][s], __fmul_rn(__fsub_rn(1.f, m2), dmax));
            g[gg][s] = __float_as_uint(adj);
        }
        uint32_t nv = g[gg][0], nw = 0;
#pragma unroll
        for (int s = 1; s < 8; ++s)
            if (g[gg][s] < nv) { nv = g[gg][s]; nw = (uint32_t)s; }
        gmv[gg] = nv; gmw[gg] = nw;
    }

    const int rk = row * Kv;
    for (int p = 0; p < Kv; ++p) {
        // lane best over the 4 cached group minima (lowest group wins ties)
        uint32_t bv = gmv[0], bg = 0, bs = gmw[0];
        if (gmv[1] < bv) { bv = gmv[1]; bg = 1; bs = gmw[1]; }
        if (gmv[2] < bv) { bv = gmv[2]; bg = 2; bs = gmw[2]; }
        if (gmv[3] < bv) { bv = gmv[3]; bg = 3; bs = gmw[3]; }
        uint32_t myj = (((bg << 3) + bs) << 6) | (uint32_t)lane;

        // wave min of value (u32, monotonic for nonneg floats)
        uint32_t mv = bv;
#pragma unroll
        for (int m = 1; m < 64; m <<= 1) {
            uint32_t o = __shfl_xor(mv, m, 64);
            mv = (o < mv) ? o : mv;
        }
        // resolve winning global index (lowest j among value-ties)
        uint32_t cand = (bv == mv) ? myj : 0xFFFFFFFFu;
#pragma unroll
        for (int m = 1; m < 64; m <<= 1) {
            uint32_t o = __shfl_xor(cand, m, 64);
            cand = (o < cand) ? o : cand;
        }
        const uint32_t mj = cand;

        if (lane == 0) {
            idx_ws[rk + p] = (int)mj;
            dn_ws[rk + p] = __uint_as_float(mv);
            idxf_out[rk + p] = (float)mj;
        }

        // owner lane invalidates + rescans its group (one lane active)
        if ((mj & 63u) == (uint32_t)lane) {
            const uint32_t ww = mj >> 6;
            const uint32_t og = ww >> 3;
            const uint32_t os = ww & 7u;
#define RESCAN(G)                                                         \
            {                                                             \
                uint32_t nv = 0xFFFFFFFFu, nw = 0;                        \
                _Pragma("unroll")                                         \
                for (int s = 0; s < 8; ++s) {                             \
                    uint32_t val = ((uint32_t)s == os) ? 0xFFFFFFFFu      \
                                                       : g[G][s];         \
                    g[G][s] = val;                                        \
                    if (val < nv) { nv = val; nw = (uint32_t)s; }         \
                }                                                         \
                gmv[G] = nv; gmw[G] = nw;                                 \
            }
            if (og == 0) RESCAN(0)
            else if (og == 1) RESCAN(1)
            else if (og == 2) RESCAN(2)
            else RESCAN(3)
#undef RESCAN
        }
    }
}

// ---------------- Kernel C: block per (b,n): features + GEMM + LN ----------------
__device__ __forceinline__ float sgnf(float x) {
    return (x > 0.f) ? 1.f : ((x < 0.f) ? -1.f : 0.f);
}

__global__ __launch_bounds__(256) void edge_kernel(const float* __restrict__ X,
                                                   const float* __restrict__ W,
                                                   const float* __restrict__ be,
                                                   const float* __restrict__ gain,
                                                   const float* __restrict__ bias,
                                                   const float* __restrict__ O9,
                                                   const int* __restrict__ idx_ws,
                                                   const float* __restrict__ dn_ws,
                                                   float* __restrict__ E) {
    __shared__ float fls[Kv][40];
    __shared__ float els[Kv][DIMv];
    __shared__ float sO[9];
    __shared__ float sX[3];
    __shared__ int   sidx[Kv];
    __shared__ float sdn[Kv];

    const int t = threadIdx.x;
    const int row = blockIdx.x;
    const int b = row >> 11;
    const int n = row & (Nv - 1);
    const int bN = b * Nv;
    const size_t ebase = (size_t)row * Kv;

    if (t < Kv) {
        sidx[t] = idx_ws[ebase + t];
        sdn[t] = dn_ws[ebase + t];
    } else if (t >= 32 && t < 41) {
        sO[t - 32] = O9[(size_t)row * 9 + (t - 32)];
    } else if (t >= 48 && t < 51) {
        sX[t - 48] = X[(size_t)row * 3 + (t - 48)];
    }
    __syncthreads();

    if (t < 240) {
        const int e = t >> 3;
        const int p = t & 7;
        const float c = -0.5756462732485115f;  // -ln(10000)/16
        float freq = expf((float)(2 * p) * c);
        float ang = ((float)sidx[e] - (float)n) * freq;
        fls[e][p] = cosf(ang);
        fls[e][p + 8] = sinf(ang);
        float dn = sdn[e];
        float mu0 = (float)p * (20.0f / 15.0f);
        float z0 = (dn - mu0) * 0.8f;
        fls[e][16 + p] = expf(-z0 * z0);
        float mu1 = (float)(p + 8) * (20.0f / 15.0f);
        float z1 = (dn - mu1) * 0.8f;
        fls[e][24 + p] = expf(-z1 * z1);
    }
    if (t < Kv) {
        const int e = t;
        const int j = sidx[e];
        float oi[9], oj[9];
#pragma unroll
        for (int i = 0; i < 9; ++i) {
            oi[i] = sO[i];
            oj[i] = O9[((size_t)bN + j) * 9 + i];
        }
        float dx = X[((size_t)bN + j) * 3 + 0] - sX[0];
        float dy = X[((size_t)bN + j) * 3 + 1] - sX[1];
        float dz = X[((size_t)bN + j) * 3 + 2] - sX[2];
        float u0 = oi[0] * dx + oi[1] * dy + oi[2] * dz;
        float u1 = oi[3] * dx + oi[4] * dy + oi[5] * dz;
        float u2 = oi[6] * dx + oi[7] * dy + oi[8] * dz;
        float un = fmaxf(sqrtf(u0 * u0 + u1 * u1 + u2 * u2), 1e-12f);
        fls[e][32] = u0 / un;
        fls[e][33] = u1 / un;
        fls[e][34] = u2 / un;
        float R00 = oi[0] * oj[0] + oi[3] * oj[3] + oi[6] * oj[6];
        float R11 = oi[1] * oj[1] + oi[4] * oj[4] + oi[7] * oj[7];
        float R22 = oi[2] * oj[2] + oi[5] * oj[5] + oi[8] * oj[8];
        float R21 = oi[2] * oj[1] + oi[5] * oj[4] + oi[8] * oj[7];
        float R12 = oi[1] * oj[2] + oi[4] * oj[5] + oi[7] * oj[8];
        float R02 = oi[0] * oj[2] + oi[3] * oj[5] + oi[6] * oj[8];
        float R20 = oi[2] * oj[0] + oi[5] * oj[3] + oi[8] * oj[6];
        float R10 = oi[1] * oj[0] + oi[4] * oj[3] + oi[7] * oj[6];
        float R01 = oi[0] * oj[1] + oi[3] * oj[4] + oi[6] * oj[7];
        float m0 = 0.5f * sqrtf(fabsf(1.0f + (R00 - R11 - R22)));
        float m1 = 0.5f * sqrtf(fabsf(1.0f + (-R00 + R11 - R22)));
        float m2 = 0.5f * sqrtf(fabsf(1.0f + (-R00 - R11 + R22)));
        float s0 = sgnf(R21 - R12);
        float s1 = sgnf(R02 - R20);
        float s2 = sgnf(R10 - R01);
        float tr = 1.0f + R00 + R11 + R22;
        float w4 = sqrtf(fmaxf(tr, 0.f)) * 0.5f;
        float q0 = s0 * m0, q1 = s1 * m1, q2 = s2 * m2;
        float qn = fmaxf(sqrtf(q0 * q0 + q1 * q1 + q2 * q2 + w4 * w4), 1e-12f);
        fls[e][35] = q0 / qn;
        fls[e][36] = q1 / qn;
        fls[e][37] = q2 / qn;
        fls[e][38] = w4 / qn;
    }
    __syncthreads();

    {
        const int c = t & 127;
        const int h = t >> 7;
        float w[39];
#pragma unroll
        for (int i = 0; i < 39; ++i) w[i] = W[i * DIMv + c];
        const float bec = be[c];
        const int e0 = h * 15;
#pragma unroll 3
        for (int e = e0; e < e0 + 15; ++e) {
            const float* fr = &fls[e][0];
            float acc = bec;
#pragma unroll
            for (int q = 0; q < 9; ++q) {
                float4 v = *(const float4*)(fr + 4 * q);
                acc = fmaf(v.x, w[4 * q + 0], acc);
                acc = fmaf(v.y, w[4 * q + 1], acc);
                acc = fmaf(v.z, w[4 * q + 2], acc);
                acc = fmaf(v.w, w[4 * q + 3], acc);
            }
            acc = fmaf(fr[36], w[36], acc);
            acc = fmaf(fr[37], w[37], acc);
            acc = fmaf(fr[38], w[38], acc);
            els[e][c] = acc;
        }
    }
    __syncthreads();

    if (t < 240) {
        const int e = t >> 3;
        const int l = t & 7;
        const float* er = &els[e][l * 16];
        float vals[16];
        float s = 0.f;
#pragma unroll
        for (int q = 0; q < 4; ++q) {
            float4 v = *(const float4*)(er + 4 * q);
            vals[4 * q + 0] = v.x; vals[4 * q + 1] = v.y;
            vals[4 * q + 2] = v.z; vals[4 * q + 3] = v.w;
            s += v.x + v.y + v.z + v.w;
        }
        s += __shfl_xor(s, 1, 64);
        s += __shfl_xor(s, 2, 64);
        s += __shfl_xor(s, 4, 64);
        float mu = s * (1.0f / 128.0f);
        float vv = 0.f;
#pragma unroll
        for (int j = 0; j < 16; ++j) {
            float d = vals[j] - mu;
            vals[j] = d;
            vv += d * d;
        }
        vv += __shfl_xor(vv, 1, 64);
        vv += __shfl_xor(vv, 2, 64);
        vv += __shfl_xor(vv, 4, 64);
        float sigma = sqrtf(vv * (1.0f / 127.0f));
        float inv = 1.0f / (sigma + 1e-6f);
        float* out = E + (ebase + e) * DIMv + l * 16;
        const float* gp = gain + l * 16;
        const float* bp = bias + l * 16;
#pragma unroll
        for (int q = 0; q < 4; ++q) {
            float4 g = *(const float4*)(gp + 4 * q);
            float4 bb = *(const float4*)(bp + 4 * q);
            float4 r;
            r.x = g.x * vals[4 * q + 0] * inv + bb.x;
            r.y = g.y * vals[4 * q + 1] * inv + bb.y;
            r.z = g.z * vals[4 * q + 2] * inv + bb.z;
            r.w = g.w * vals[4 * q + 3] * inv + bb.w;
            *(float4*)(out + 4 * q) = r;
        }
    }
}

// ---------------- launcher ----------------
extern "C" void kernel_launch(void* const* d_in, const int* in_sizes, int n_in,
                              void* d_out, int out_size, void* d_ws, size_t ws_size,
                              hipStream_t stream) {
    const float* X = (const float*)d_in[0];
    const float* mask = (const float*)d_in[1];
    const float* W_e = (const float*)d_in[2];
    const float* b_e = (const float*)d_in[3];
    const float* gain = (const float*)d_in[4];
    const float* bias = (const float*)d_in[5];

    float* E = (float*)d_out;
    float* idxf = (float*)d_out + (size_t)NEDGE * DIMv;

    char* ws = (char*)d_ws;
    float* O9 = (float*)ws;
    int* idx_ws = (int*)(ws + (size_t)NROW * 9 * sizeof(float));
    float* dn_ws = (float*)(ws + (size_t)NROW * 9 * sizeof(float) +
                            (size_t)NEDGE * sizeof(int));

    hipLaunchKernelGGL(o_kernel, dim3((NROW + 255) / 256), dim3(256), 0, stream, X, O9);
    hipLaunchKernelGGL(topk_kernel, dim3(NROW / 4), dim3(256), 0, stream,
                       X, mask, idx_ws, dn_ws, idxf);
    hipLaunchKernelGGL(edge_kernel, dim3(NROW), dim3(256), 0, stream,
                       X, W_e, b_e, gain, bias, O9, idx_ws, dn_ws, E);
}